// Round 7
// baseline (216.959 us; speedup 1.0000x reference)
//
#include <hip/hip_runtime.h>

typedef _Float16 half8 __attribute__((ext_vector_type(8)));
typedef _Float16 half2v __attribute__((ext_vector_type(2)));
typedef float float4v __attribute__((ext_vector_type(4)));

// ---- helpers ----
__device__ __forceinline__ float dot2acc(unsigned a, unsigned b, float c) {
#if __has_builtin(__builtin_amdgcn_fdot2)
  return __builtin_amdgcn_fdot2(__builtin_bit_cast(half2v, a), __builtin_bit_cast(half2v, b), c, false);
#else
  half2v ha = __builtin_bit_cast(half2v, a);
  half2v hb = __builtin_bit_cast(half2v, b);
  c += (float)ha[0] * (float)hb[0];
  c += (float)ha[1] * (float)hb[1];
  return c;
#endif
}
__device__ __forceinline__ unsigned pack2(float a, float b) {
  half2v h;
  h[0] = (_Float16)a;
  h[1] = (_Float16)b;
  return __builtin_bit_cast(unsigned, h);
}
__device__ __forceinline__ void gload_lds16(const void* g, void* l) {
  __builtin_amdgcn_global_load_lds((const __attribute__((address_space(1))) unsigned*)g,
                                   (__attribute__((address_space(3))) unsigned*)l, 16, 0, 0);
}
__device__ __forceinline__ void sbar0() { __builtin_amdgcn_sched_barrier(0); }
#define WAITVM(n) asm volatile("s_waitcnt vmcnt(" #n ")" ::: "memory")
#define WAITLGKM asm volatile("s_waitcnt lgkmcnt(0)" ::: "memory")

__device__ __forceinline__ void cvt_store8(_Float16* dst, float4 a, float4 b) {
  half8 h;
  h[0] = (_Float16)a.x; h[1] = (_Float16)a.y; h[2] = (_Float16)a.z; h[3] = (_Float16)a.w;
  h[4] = (_Float16)b.x; h[5] = (_Float16)b.y; h[6] = (_Float16)b.z; h[7] = (_Float16)b.w;
  *(half8*)dst = h;
}

// ---- fp32 -> fp16 convert, WEIGHTS ONLY ----
__global__ void cvt_w(const float4* __restrict__ wqk, const float4* __restrict__ wpj,
                      ushort4* __restrict__ wqk16, ushort4* __restrict__ wpj16) {
  int b = blockIdx.x;
  const float4* s;
  ushort4* d;
  int i;
  if (b < 128) { s = wqk; d = wqk16; i = b * 256 + threadIdx.x; }
  else { s = wpj; d = wpj16; i = (b - 128) * 256 + threadIdx.x; }
  float4 v = s[i];
  _Float16 a = (_Float16)v.x, bb = (_Float16)v.y, c = (_Float16)v.z, e = (_Float16)v.w;
  ushort4 o;
  o.x = __builtin_bit_cast(unsigned short, a);
  o.y = __builtin_bit_cast(unsigned short, bb);
  o.z = __builtin_bit_cast(unsigned short, c);
  o.w = __builtin_bit_cast(unsigned short, e);
  d[i] = o;
}

// ---- GEMM1: qk = x(fp32, cvt in-register) @ wqk16^T. 128x256 tile, 512 thr.
// Counted-vmcnt pipeline (T4): raw s_barrier, 2-deep x prefetch, B via gload_lds
// retired by vmcnt(2) -- never drains to 0 in the loop. XCD-pair block swizzle so
// both column-blocks of an x row-panel share an XCD L2. Epilogue fuses L2-normalize.
__global__ __launch_bounds__(512, 4)
void gemm_qk(const float* __restrict__ X, const _Float16* __restrict__ Bw,
             _Float16* __restrict__ qo, _Float16* __restrict__ ko) {
  __shared__ _Float16 Ash[2][4096];   // 128 rows x 32 k
  __shared__ _Float16 Bsh[2][8192];   // 256 rows x 32 k
  const int tid = threadIdx.x;
  const int lane = tid & 63, w = tid >> 6;
  const int wm = w >> 2, wn = w & 3;
  const int ml = lane & 15, qd = lane >> 4;
  const int bid = blockIdx.x;
  const int yb = ((bid >> 4) << 3) | (bid & 7);   // bids d and d+8: same y, same XCD
  const int xb = (bid >> 3) & 1;
  const int m0 = yb * 128, n0 = xb * 256;

  float4v acc[4][4];
  float4v z = {0.f, 0.f, 0.f, 0.f};
#pragma unroll
  for (int i = 0; i < 4; ++i)
#pragma unroll
    for (int j = 0; j < 4; ++j) acc[i][j] = z;

  const float* Xp = X + (size_t)m0 * 256;
  const _Float16* Bp = Bw + (size_t)n0 * 256;
  const int ar = tid >> 2, aj = tid & 3;
  const int ajx = aj ^ ((ar >> 1) & 3);
  const int rB0 = tid >> 2, jB0 = (tid & 3) ^ ((rB0 >> 1) & 3);
  const int rB1 = rB0 + 128, jB1 = (tid & 3) ^ ((rB1 >> 1) & 3);

  float4 xs[2][2];
  // prologue: B(0) async; x(0), x(1) to regs; stage A(0); single full barrier
  gload_lds16(Bp + rB0 * 256 + jB0 * 8, &Bsh[0][(size_t)(w * 64) * 8]);
  gload_lds16(Bp + rB1 * 256 + jB1 * 8, &Bsh[0][(size_t)(512 + w * 64) * 8]);
  sbar0();
  xs[0][0] = *(const float4*)(Xp + (size_t)ar * 256 + ajx * 8);
  xs[0][1] = *(const float4*)(Xp + (size_t)ar * 256 + ajx * 8 + 4);
  sbar0();
  xs[1][0] = *(const float4*)(Xp + (size_t)ar * 256 + 32 + ajx * 8);
  xs[1][1] = *(const float4*)(Xp + (size_t)ar * 256 + 32 + ajx * 8 + 4);
  WAITVM(2);  // retires B(0)+x(0); x(1) stays in flight
  sbar0();
  cvt_store8(&Ash[0][ar * 32 + aj * 8], xs[0][0], xs[0][1]);
  WAITLGKM;
  sbar0();
  __builtin_amdgcn_s_barrier();
  sbar0();

#pragma unroll
  for (int kt = 0; kt < 8; ++kt) {
    const int cur = kt & 1, nbuf = cur ^ 1;
    const int kB = (kt + 1 < 8 ? kt + 1 : 7) * 32;   // clamped: uniform vm counts
    const int kX = (kt + 2 < 8 ? kt + 2 : 7) * 32;
    gload_lds16(Bp + rB0 * 256 + kB + jB0 * 8, &Bsh[nbuf][(size_t)(w * 64) * 8]);
    gload_lds16(Bp + rB1 * 256 + kB + jB1 * 8, &Bsh[nbuf][(size_t)(512 + w * 64) * 8]);
    sbar0();
    xs[kt & 1][0] = *(const float4*)(Xp + (size_t)ar * 256 + kX + ajx * 8);
    xs[kt & 1][1] = *(const float4*)(Xp + (size_t)ar * 256 + kX + ajx * 8 + 4);
    half8 af[4], bf[4];
#pragma unroll
    for (int im = 0; im < 4; ++im) {
      int rr = wm * 64 + im * 16 + ml;
      af[im] = *(const half8*)(&Ash[cur][rr * 32 + (qd ^ ((rr >> 1) & 3)) * 8]);
      int rc = wn * 64 + im * 16 + ml;
      bf[im] = *(const half8*)(&Bsh[cur][rc * 32 + (qd ^ ((rc >> 1) & 3)) * 8]);
    }
#pragma unroll
    for (int im = 0; im < 4; ++im)
#pragma unroll
      for (int in = 0; in < 4; ++in)
        acc[im][in] = __builtin_amdgcn_mfma_f32_16x16x32_f16(bf[in], af[im], acc[im][in], 0, 0, 0);
    WAITVM(2);  // retires x(kt+1) and B(kt+1); leaves x(kt+2) in flight
    sbar0();
    cvt_store8(&Ash[nbuf][ar * 32 + aj * 8], xs[(kt + 1) & 1][0], xs[(kt + 1) & 1][1]);
    WAITLGKM;
    sbar0();
    __builtin_amdgcn_s_barrier();
    sbar0();
  }

  // epilogue: D[row = ml][col = qd*4+r]; fused L2-normalize per (row, head).
#pragma unroll
  for (int im = 0; im < 4; ++im) {
    int rowr = m0 + wm * 64 + im * 16 + ml;
    int b = rowr >> 13, n = rowr & 8191;
    int t = n >> 10, yx = n & 1023;
#pragma unroll
    for (int hh = 0; hh < 2; ++hh) {
      float ss = 0.f;
#pragma unroll
      for (int ii = 0; ii < 2; ++ii) {
        int in = hh * 2 + ii;
#pragma unroll
        for (int r = 0; r < 4; ++r) ss += acc[im][in][r] * acc[im][in][r];
      }
      ss += __shfl_xor(ss, 16);
      ss += __shfl_xor(ss, 32);
      float sc = 1.f / fmaxf(sqrtf(ss), 1e-12f);
#pragma unroll
      for (int ii = 0; ii < 2; ++ii) {
        int in = hh * 2 + ii;
        int col = n0 + wn * 64 + in * 16 + qd * 4;
        int s = col >> 8, h = (col >> 5) & 7, j = col & 31;
        _Float16* dst = s ? ko : qo;
        int p = b * 64 + h * 8 + t;
        uint2 pk;
        pk.x = pack2(acc[im][in][0] * sc, acc[im][in][1] * sc);
        pk.y = pack2(acc[im][in][2] * sc, acc[im][in][3] * sc);
        *(uint2*)(dst + ((size_t)p * 1024 + yx) * 32 + j) = pk;
      }
    }
  }
}

// ---- correlation + (corr @ w_corr^T + b_corr) fused. q16/k16 arrive pre-normalized.
// grid: 512 volumes * 4 tiles of 16x16; block 256; LDS 40960B -> 4 blocks/CU
__global__ __launch_bounds__(256, 4)
void corr_kernel(const _Float16* __restrict__ q16, const _Float16* __restrict__ k16,
                 const float* __restrict__ wcorr, const float* __restrict__ bcorr,
                 _Float16* __restrict__ outp) {
  __shared__ uint4 smem[2304];  // k-tile (1936 granules) then reused as corr matrix [256][72] halfs
  __shared__ uint4 wcs[256];    // w_corr fp16 [32][64]: 49 taps + bias at k=49 + zero pad

  const int tid = threadIdx.x;
  const int bx = blockIdx.x;
  const int p = bx >> 2, tile = bx & 3;
  const int y0 = (tile >> 1) * 16, x0 = (tile & 1) * 16;
  const int b = p >> 6, h = (p >> 3) & 7, t = p & 7;
  const int pk = (t < 7) ? p + 1 : p;
  const int ty = tid >> 4, tx = tid & 15;

  // stage w_corr (fp16, K padded to 64 with bias folded in at k=49)
  _Float16* wch = (_Float16*)wcs;
  for (int idx = tid; idx < 2048; idx += 256) {
    int d = idx >> 6, kk = idx & 63;
    float v = (kk < 49) ? wcorr[d * 49 + kk] : (kk == 49 ? bcorr[d] : 0.f);
    wch[idx] = (_Float16)v;
  }

  // stage k tile 22x22 vectors of 32 halfs (4 granules each), swizzled
  const _Float16* kbase = k16 + (size_t)pk * 32768;
#pragma unroll
  for (int i = 0; i < 8; ++i) {
    int g = tid + i * 256;
    if (g < 1936) {
      int vec = g >> 2, part = g & 3;
      int ky = vec / 22, kx = vec - ky * 22;
      int gy = y0 + ky - 3, gx = x0 + kx - 3;
      uint4 val = make_uint4(0u, 0u, 0u, 0u);
      if (gy >= 0 && gy < 32 && gx >= 0 && gx < 32)
        val = *(const uint4*)(kbase + ((size_t)gy * 32 + gx) * 32 + part * 8);
      int slot = (vec << 2) | (part ^ (vec & 3) ^ ((vec >> 2) & 3));
      smem[slot] = val;
    }
  }

  // per-thread q vector (pre-normalized fp16)
  const _Float16* qptr = q16 + (size_t)p * 32768 + ((size_t)(y0 + ty) * 32 + (x0 + tx)) * 32;
  uint4 qv[4];
#pragma unroll
  for (int i = 0; i < 4; ++i) qv[i] = *(const uint4*)(qptr + i * 8);
  unsigned* qu = (unsigned*)qv;
  __syncthreads();

  // 49 correlations via v_dot2_f32_f16
  float corr[49];
#pragma unroll
  for (int dy = 0; dy < 7; ++dy) {
#pragma unroll
    for (int dx = 0; dx < 7; ++dx) {
      int vec = (ty + dy) * 22 + (tx + dx);
      int base = vec << 2;
      int sw = (vec & 3) ^ ((vec >> 2) & 3);
      float c = 0.f;
#pragma unroll
      for (int pq = 0; pq < 4; ++pq) {
        uint4 kk = smem[base | (pq ^ sw)];
        const unsigned* ku = (const unsigned*)&kk;
#pragma unroll
        for (int e = 0; e < 4; ++e) c = dot2acc(qu[pq * 4 + e], ku[e], c);
      }
      corr[dy * 7 + dx] = c;
    }
  }
  __syncthreads();  // all k-tile reads done; smem reused as corr matrix

  // write corr row (pos = tid) as fp16: 49 taps, 1.0 at k=49 (bias), zeros to 63.
#pragma unroll
  for (int i = 0; i < 8; ++i) {
    uint4 val;
    unsigned* vu = (unsigned*)&val;
#pragma unroll
    for (int e = 0; e < 4; ++e) {
      int idx = i * 8 + e * 2;
      half2v hh;
      hh[0] = (_Float16)(idx < 49 ? corr[idx] : (idx == 49 ? 1.f : 0.f));
      hh[1] = (_Float16)(idx + 1 < 49 ? corr[idx + 1] : (idx + 1 == 49 ? 1.f : 0.f));
      vu[e] = __builtin_bit_cast(unsigned, hh);
    }
    smem[tid * 9 + i] = val;
  }
  __syncthreads();

  // MFMA: (256 pos x 64k) @ (64k x 32d): wave w handles m-tiles 4w..4w+3, 2 n-tiles
  _Float16* corrm = (_Float16*)smem;
  const int lane = tid & 63, w = tid >> 6;
  const int ml = lane & 15, qd = lane >> 4;
  float4v vacc[4][2];
  float4v z = {0.f, 0.f, 0.f, 0.f};
#pragma unroll
  for (int im = 0; im < 4; ++im) { vacc[im][0] = z; vacc[im][1] = z; }
#pragma unroll
  for (int ks = 0; ks < 2; ++ks) {
    half8 bfrag[2];
#pragma unroll
    for (int nt = 0; nt < 2; ++nt)
      bfrag[nt] = *(const half8*)(wch + (nt * 16 + ml) * 64 + ks * 32 + qd * 8);
#pragma unroll
    for (int im = 0; im < 4; ++im) {
      half8 afrag = *(const half8*)(corrm + (w * 64 + im * 16 + ml) * 72 + ks * 32 + qd * 8);
#pragma unroll
      for (int nt = 0; nt < 2; ++nt)
        vacc[im][nt] = __builtin_amdgcn_mfma_f32_16x16x32_f16(afrag, bfrag[nt], vacc[im][nt], 0, 0, 0);
    }
  }

  // epilogue: v -> outpre[b, n, h*32+d] fp16 (bias already folded via K=49 column)
#pragma unroll
  for (int im = 0; im < 4; ++im) {
#pragma unroll
    for (int nt = 0; nt < 2; ++nt) {
      int d = nt * 16 + ml;
#pragma unroll
      for (int r = 0; r < 4; ++r) {
        int pos = w * 64 + im * 16 + qd * 4 + r;
        int py = pos >> 4, px = pos & 15;
        int n = t * 1024 + (y0 + py) * 32 + (x0 + px);
        outp[(((size_t)b * 8192 + n) << 8) + h * 32 + d] = (_Float16)vacc[im][nt][r];
      }
    }
  }
}

// ---- proj GEMM: out = op16 @ wproj16^T + b_proj. 128x256 tile = FULL output width.
// Counted-vmcnt pipeline: A reg-staged 2-deep, B gload_lds retired by vmcnt(1).
__global__ __launch_bounds__(512, 4)
void gemm_proj(const _Float16* __restrict__ A, const _Float16* __restrict__ Bw,
               const float* __restrict__ bp, float* __restrict__ out) {
  __shared__ _Float16 Ash[2][4096];
  __shared__ _Float16 Bsh[2][8192];
  const int tid = threadIdx.x;
  const int lane = tid & 63, w = tid >> 6;
  const int wm = w >> 2, wn = w & 3;
  const int ml = lane & 15, qd = lane >> 4;
  const int m0 = blockIdx.x * 128;

  float4v acc[4][4];
  float4v z = {0.f, 0.f, 0.f, 0.f};
#pragma unroll
  for (int i = 0; i < 4; ++i)
#pragma unroll
    for (int j = 0; j < 4; ++j) acc[i][j] = z;

  const _Float16* Ap = A + (size_t)m0 * 256;
  const _Float16* Bp = Bw;
  const int ar = tid >> 2, aj = tid & 3;
  const int ajx = aj ^ ((ar >> 1) & 3);
  const int rB0 = tid >> 2, jB0 = (tid & 3) ^ ((rB0 >> 1) & 3);
  const int rB1 = rB0 + 128, jB1 = (tid & 3) ^ ((rB1 >> 1) & 3);

  uint4 as[2];
  gload_lds16(Bp + rB0 * 256 + jB0 * 8, &Bsh[0][(size_t)(w * 64) * 8]);
  gload_lds16(Bp + rB1 * 256 + jB1 * 8, &Bsh[0][(size_t)(512 + w * 64) * 8]);
  sbar0();
  as[0] = *(const uint4*)(Ap + (size_t)ar * 256 + ajx * 8);
  sbar0();
  as[1] = *(const uint4*)(Ap + (size_t)ar * 256 + 32 + ajx * 8);
  WAITVM(1);  // retires B(0)+A(0); A(1) stays in flight
  sbar0();
  *(uint4*)(&Ash[0][ar * 32 + aj * 8]) = as[0];
  WAITLGKM;
  sbar0();
  __builtin_amdgcn_s_barrier();
  sbar0();

#pragma unroll
  for (int kt = 0; kt < 8; ++kt) {
    const int cur = kt & 1, nbuf = cur ^ 1;
    const int kB = (kt + 1 < 8 ? kt + 1 : 7) * 32;
    const int kA = (kt + 2 < 8 ? kt + 2 : 7) * 32;
    gload_lds16(Bp + rB0 * 256 + kB + jB0 * 8, &Bsh[nbuf][(size_t)(w * 64) * 8]);
    gload_lds16(Bp + rB1 * 256 + kB + jB1 * 8, &Bsh[nbuf][(size_t)(512 + w * 64) * 8]);
    sbar0();
    as[kt & 1] = *(const uint4*)(Ap + (size_t)ar * 256 + kA + ajx * 8);
    half8 af[4], bf[4];
#pragma unroll
    for (int im = 0; im < 4; ++im) {
      int rr = wm * 64 + im * 16 + ml;
      af[im] = *(const half8*)(&Ash[cur][rr * 32 + (qd ^ ((rr >> 1) & 3)) * 8]);
      int rc = wn * 64 + im * 16 + ml;
      bf[im] = *(const half8*)(&Bsh[cur][rc * 32 + (qd ^ ((rc >> 1) & 3)) * 8]);
    }
#pragma unroll
    for (int im = 0; im < 4; ++im)
#pragma unroll
      for (int in = 0; in < 4; ++in)
        acc[im][in] = __builtin_amdgcn_mfma_f32_16x16x32_f16(bf[in], af[im], acc[im][in], 0, 0, 0);
    WAITVM(1);  // retires A(kt+1) and B(kt+1); leaves A(kt+2)
    sbar0();
    *(uint4*)(&Ash[nbuf][ar * 32 + aj * 8]) = as[(kt + 1) & 1];
    WAITLGKM;
    sbar0();
    __builtin_amdgcn_s_barrier();
    sbar0();
  }

  // epilogue: lane covers row rowr, 4 consecutive cols -> one 16B store
#pragma unroll
  for (int im = 0; im < 4; ++im) {
    int rowr = m0 + wm * 64 + im * 16 + ml;
#pragma unroll
    for (int in = 0; in < 4; ++in) {
      int col = wn * 64 + in * 16 + qd * 4;
      float4 bb = *(const float4*)(bp + col);
      float4 o;
      o.x = acc[im][in][0] + bb.x;
      o.y = acc[im][in][1] + bb.y;
      o.z = acc[im][in][2] + bb.z;
      o.w = acc[im][in][3] + bb.w;
      *(float4*)(out + (size_t)rowr * 256 + col) = o;
    }
  }
}

extern "C" void kernel_launch(void* const* d_in, const int* in_sizes, int n_in,
                              void* d_out, int out_size, void* d_ws, size_t ws_size,
                              hipStream_t stream) {
  const float* x      = (const float*)d_in[0];
  const float* w_qk   = (const float*)d_in[1];
  const float* w_corr = (const float*)d_in[2];
  const float* b_corr = (const float*)d_in[3];
  const float* w_proj = (const float*)d_in[4];
  const float* b_proj = (const float*)d_in[5];
  float* out = (float*)d_out;

  char* ws = (char*)d_ws;
  _Float16* q16   = (_Float16*)(ws + 33554432);
  _Float16* k16   = (_Float16*)(ws + 67108864);
  _Float16* op16  = (_Float16*)(ws + 100663296);
  _Float16* wqk16 = (_Float16*)(ws + 134217728);
  _Float16* wpj16 = (_Float16*)(ws + 134479872);

  cvt_w<<<192, 256, 0, stream>>>((const float4*)w_qk, (const float4*)w_proj,
                                 (ushort4*)wqk16, (ushort4*)wpj16);
  gemm_qk<<<1024, 512, 0, stream>>>(x, wqk16, q16, k16);
  corr_kernel<<<2048, 256, 0, stream>>>(q16, k16, w_corr, b_corr, op16);
  gemm_proj<<<512, 512, 0, stream>>>(op16, wpj16, b_proj, out);
}

// Round 9
// 209.269 us; speedup vs baseline: 1.0367x; 1.0367x over previous
//
#include <hip/hip_runtime.h>

typedef _Float16 half8 __attribute__((ext_vector_type(8)));
typedef _Float16 half2v __attribute__((ext_vector_type(2)));
typedef float float4v __attribute__((ext_vector_type(4)));

// ---- helpers ----
__device__ __forceinline__ float dot2acc(unsigned a, unsigned b, float c) {
#if __has_builtin(__builtin_amdgcn_fdot2)
  return __builtin_amdgcn_fdot2(__builtin_bit_cast(half2v, a), __builtin_bit_cast(half2v, b), c, false);
#else
  half2v ha = __builtin_bit_cast(half2v, a);
  half2v hb = __builtin_bit_cast(half2v, b);
  c += (float)ha[0] * (float)hb[0];
  c += (float)ha[1] * (float)hb[1];
  return c;
#endif
}
__device__ __forceinline__ unsigned pack2(float a, float b) {
  half2v h;
  h[0] = (_Float16)a;
  h[1] = (_Float16)b;
  return __builtin_bit_cast(unsigned, h);
}
__device__ __forceinline__ void sbar0() { __builtin_amdgcn_sched_barrier(0); }
#define WAITLGKM asm volatile("s_waitcnt lgkmcnt(0)" ::: "memory")

__device__ __forceinline__ void cvt_store8(_Float16* dst, float4 a, float4 b) {
  half8 h;
  h[0] = (_Float16)a.x; h[1] = (_Float16)a.y; h[2] = (_Float16)a.z; h[3] = (_Float16)a.w;
  h[4] = (_Float16)b.x; h[5] = (_Float16)b.y; h[6] = (_Float16)b.z; h[7] = (_Float16)b.w;
  *(half8*)dst = h;
}

// ---- fp32 -> fp16 convert, WEIGHTS ONLY ----
__global__ void cvt_w(const float4* __restrict__ wqk, const float4* __restrict__ wpj,
                      ushort4* __restrict__ wqk16, ushort4* __restrict__ wpj16) {
  int b = blockIdx.x;
  const float4* s;
  ushort4* d;
  int i;
  if (b < 128) { s = wqk; d = wqk16; i = b * 256 + threadIdx.x; }
  else { s = wpj; d = wpj16; i = (b - 128) * 256 + threadIdx.x; }
  float4 v = s[i];
  _Float16 a = (_Float16)v.x, bb = (_Float16)v.y, c = (_Float16)v.z, e = (_Float16)v.w;
  ushort4 o;
  o.x = __builtin_bit_cast(unsigned short, a);
  o.y = __builtin_bit_cast(unsigned short, bb);
  o.z = __builtin_bit_cast(unsigned short, c);
  o.w = __builtin_bit_cast(unsigned short, e);
  d[i] = o;
}

// ---- GEMM1: qk = x(fp32, cvt in-register) @ wqk16^T. 128x256 tile, 512 thr.
// Full reg-staged 2-deep pipeline (T14): loads for tile kt+2 issued each step,
// ds_write of tile kt+1 after the MFMAs (one K-step of latency cover for BOTH
// operands), raw s_barrier with only lgkmcnt(0) (in-flight global loads cross the
// barrier). XCD-pair swizzle; epilogue fuses per-(row,head) L2 normalization.
__global__ __launch_bounds__(512)
void gemm_qk(const float* __restrict__ X, const _Float16* __restrict__ Bw,
             _Float16* __restrict__ qo, _Float16* __restrict__ ko) {
  __shared__ _Float16 Ash[2][4096];   // 128 rows x 32 k
  __shared__ _Float16 Bsh[2][8192];   // 256 rows x 32 k
  const int tid = threadIdx.x;
  const int lane = tid & 63, w = tid >> 6;
  const int wm = w >> 2, wn = w & 3;
  const int ml = lane & 15, qd = lane >> 4;
  const int bid = blockIdx.x;
  const int yb = ((bid >> 4) << 3) | (bid & 7);   // bids d and d+8: same y, same XCD
  const int xb = (bid >> 3) & 1;
  const int m0 = yb * 128, n0 = xb * 256;

  float4v acc[4][4];
  float4v z = {0.f, 0.f, 0.f, 0.f};
#pragma unroll
  for (int i = 0; i < 4; ++i)
#pragma unroll
    for (int j = 0; j < 4; ++j) acc[i][j] = z;

  const float* Xp = X + (size_t)m0 * 256;
  const _Float16* Bp = Bw + (size_t)n0 * 256;
  // A granule: thread tid -> phys granule (ar,aj), global logical col ajx (XOR swizzle)
  const int ar = tid >> 2, aj = tid & 3;
  const int ajx = aj ^ ((ar >> 1) & 3);
  // B granules g0=tid, g1=tid+512 (phys-linear LDS; global col pre-swizzled)
  const int rB0 = tid >> 2, jB0 = (tid & 3) ^ ((rB0 >> 1) & 3);
  const int rB1 = rB0 + 128, jB1 = (tid & 3) ^ ((rB1 >> 1) & 3);

  float4 xs[2][2];
  uint4 bs[2][2];

  // prologue: tile0 -> regs -> buf0 ; tile1 -> regs (stays); one barrier
  xs[0][0] = *(const float4*)(Xp + (size_t)ar * 256 + ajx * 8);
  xs[0][1] = *(const float4*)(Xp + (size_t)ar * 256 + ajx * 8 + 4);
  bs[0][0] = *(const uint4*)(Bp + (size_t)rB0 * 256 + jB0 * 8);
  bs[0][1] = *(const uint4*)(Bp + (size_t)rB1 * 256 + jB1 * 8);
  cvt_store8(&Ash[0][ar * 32 + aj * 8], xs[0][0], xs[0][1]);
  *(uint4*)(&Bsh[0][tid * 8]) = bs[0][0];
  *(uint4*)(&Bsh[0][(tid + 512) * 8]) = bs[0][1];
  xs[1][0] = *(const float4*)(Xp + (size_t)ar * 256 + 32 + ajx * 8);
  xs[1][1] = *(const float4*)(Xp + (size_t)ar * 256 + 32 + ajx * 8 + 4);
  bs[1][0] = *(const uint4*)(Bp + (size_t)rB0 * 256 + 32 + jB0 * 8);
  bs[1][1] = *(const uint4*)(Bp + (size_t)rB1 * 256 + 32 + jB1 * 8);
  WAITLGKM;
  sbar0();
  __builtin_amdgcn_s_barrier();
  sbar0();

#pragma unroll
  for (int kt = 0; kt < 8; ++kt) {
    const int cur = kt & 1, nbuf = cur ^ 1;
    if (kt < 6) {
      const int kX = (kt + 2) * 32;
      xs[kt & 1][0] = *(const float4*)(Xp + (size_t)ar * 256 + kX + ajx * 8);
      xs[kt & 1][1] = *(const float4*)(Xp + (size_t)ar * 256 + kX + ajx * 8 + 4);
      bs[kt & 1][0] = *(const uint4*)(Bp + (size_t)rB0 * 256 + kX + jB0 * 8);
      bs[kt & 1][1] = *(const uint4*)(Bp + (size_t)rB1 * 256 + kX + jB1 * 8);
      sbar0();  // pin load issue here
    }
    half8 af[4], bf[4];
#pragma unroll
    for (int im = 0; im < 4; ++im) {
      int rr = wm * 64 + im * 16 + ml;
      af[im] = *(const half8*)(&Ash[cur][rr * 32 + (qd ^ ((rr >> 1) & 3)) * 8]);
      int rc = wn * 64 + im * 16 + ml;
      bf[im] = *(const half8*)(&Bsh[cur][rc * 32 + (qd ^ ((rc >> 1) & 3)) * 8]);
    }
#pragma unroll
    for (int im = 0; im < 4; ++im)
#pragma unroll
      for (int in = 0; in < 4; ++in)
        acc[im][in] = __builtin_amdgcn_mfma_f32_16x16x32_f16(bf[in], af[im], acc[im][in], 0, 0, 0);
    if (kt < 7) {
      cvt_store8(&Ash[nbuf][ar * 32 + aj * 8], xs[(kt + 1) & 1][0], xs[(kt + 1) & 1][1]);
      *(uint4*)(&Bsh[nbuf][tid * 8]) = bs[(kt + 1) & 1][0];
      *(uint4*)(&Bsh[nbuf][(tid + 512) * 8]) = bs[(kt + 1) & 1][1];
      WAITLGKM;
      sbar0();
      __builtin_amdgcn_s_barrier();
      sbar0();
    }
  }

  // epilogue: D[row = ml][col = qd*4+r]; fused L2-normalize per (row, head).
#pragma unroll
  for (int im = 0; im < 4; ++im) {
    int rowr = m0 + wm * 64 + im * 16 + ml;
    int b = rowr >> 13, n = rowr & 8191;
    int t = n >> 10, yx = n & 1023;
#pragma unroll
    for (int hh = 0; hh < 2; ++hh) {
      float ss = 0.f;
#pragma unroll
      for (int ii = 0; ii < 2; ++ii) {
        int in = hh * 2 + ii;
#pragma unroll
        for (int r = 0; r < 4; ++r) ss += acc[im][in][r] * acc[im][in][r];
      }
      ss += __shfl_xor(ss, 16);
      ss += __shfl_xor(ss, 32);
      float sc = 1.f / fmaxf(sqrtf(ss), 1e-12f);
#pragma unroll
      for (int ii = 0; ii < 2; ++ii) {
        int in = hh * 2 + ii;
        int col = n0 + wn * 64 + in * 16 + qd * 4;
        int s = col >> 8, h = (col >> 5) & 7, j = col & 31;
        _Float16* dst = s ? ko : qo;
        int p = b * 64 + h * 8 + t;
        uint2 pk;
        pk.x = pack2(acc[im][in][0] * sc, acc[im][in][1] * sc);
        pk.y = pack2(acc[im][in][2] * sc, acc[im][in][3] * sc);
        *(uint2*)(dst + ((size_t)p * 1024 + yx) * 32 + j) = pk;
      }
    }
  }
}

// ---- correlation + (corr @ w_corr^T + b_corr) fused. q16/k16 arrive pre-normalized.
// grid: 512 volumes * 4 tiles of 16x16; block 256; LDS 40960B -> 4 blocks/CU
__global__ __launch_bounds__(256, 4)
void corr_kernel(const _Float16* __restrict__ q16, const _Float16* __restrict__ k16,
                 const float* __restrict__ wcorr, const float* __restrict__ bcorr,
                 _Float16* __restrict__ outp) {
  __shared__ uint4 smem[2304];  // k-tile (1936 granules) then reused as corr matrix [256][72] halfs
  __shared__ uint4 wcs[256];    // w_corr fp16 [32][64]: 49 taps + bias at k=49 + zero pad

  const int tid = threadIdx.x;
  const int bx = blockIdx.x;
  const int p = bx >> 2, tile = bx & 3;
  const int y0 = (tile >> 1) * 16, x0 = (tile & 1) * 16;
  const int b = p >> 6, h = (p >> 3) & 7, t = p & 7;
  const int pk = (t < 7) ? p + 1 : p;
  const int ty = tid >> 4, tx = tid & 15;

  // stage w_corr (fp16, K padded to 64 with bias folded in at k=49)
  _Float16* wch = (_Float16*)wcs;
  for (int idx = tid; idx < 2048; idx += 256) {
    int d = idx >> 6, kk = idx & 63;
    float v = (kk < 49) ? wcorr[d * 49 + kk] : (kk == 49 ? bcorr[d] : 0.f);
    wch[idx] = (_Float16)v;
  }

  // stage k tile 22x22 vectors of 32 halfs (4 granules each), swizzled
  const _Float16* kbase = k16 + (size_t)pk * 32768;
#pragma unroll
  for (int i = 0; i < 8; ++i) {
    int g = tid + i * 256;
    if (g < 1936) {
      int vec = g >> 2, part = g & 3;
      int ky = vec / 22, kx = vec - ky * 22;
      int gy = y0 + ky - 3, gx = x0 + kx - 3;
      uint4 val = make_uint4(0u, 0u, 0u, 0u);
      if (gy >= 0 && gy < 32 && gx >= 0 && gx < 32)
        val = *(const uint4*)(kbase + ((size_t)gy * 32 + gx) * 32 + part * 8);
      int slot = (vec << 2) | (part ^ (vec & 3) ^ ((vec >> 2) & 3));
      smem[slot] = val;
    }
  }

  // per-thread q vector (pre-normalized fp16)
  const _Float16* qptr = q16 + (size_t)p * 32768 + ((size_t)(y0 + ty) * 32 + (x0 + tx)) * 32;
  uint4 qv[4];
#pragma unroll
  for (int i = 0; i < 4; ++i) qv[i] = *(const uint4*)(qptr + i * 8);
  unsigned* qu = (unsigned*)qv;
  __syncthreads();

  // 49 correlations via v_dot2_f32_f16
  float corr[49];
#pragma unroll
  for (int dy = 0; dy < 7; ++dy) {
#pragma unroll
    for (int dx = 0; dx < 7; ++dx) {
      int vec = (ty + dy) * 22 + (tx + dx);
      int base = vec << 2;
      int sw = (vec & 3) ^ ((vec >> 2) & 3);
      float c = 0.f;
#pragma unroll
      for (int pq = 0; pq < 4; ++pq) {
        uint4 kk = smem[base | (pq ^ sw)];
        const unsigned* ku = (const unsigned*)&kk;
#pragma unroll
        for (int e = 0; e < 4; ++e) c = dot2acc(qu[pq * 4 + e], ku[e], c);
      }
      corr[dy * 7 + dx] = c;
    }
  }
  __syncthreads();  // all k-tile reads done; smem reused as corr matrix

  // write corr row (pos = tid) as fp16: 49 taps, 1.0 at k=49 (bias), zeros to 63.
#pragma unroll
  for (int i = 0; i < 8; ++i) {
    uint4 val;
    unsigned* vu = (unsigned*)&val;
#pragma unroll
    for (int e = 0; e < 4; ++e) {
      int idx = i * 8 + e * 2;
      half2v hh;
      hh[0] = (_Float16)(idx < 49 ? corr[idx] : (idx == 49 ? 1.f : 0.f));
      hh[1] = (_Float16)(idx + 1 < 49 ? corr[idx + 1] : (idx + 1 == 49 ? 1.f : 0.f));
      vu[e] = __builtin_bit_cast(unsigned, hh);
    }
    smem[tid * 9 + i] = val;
  }
  __syncthreads();

  // MFMA: (256 pos x 64k) @ (64k x 32d): wave w handles m-tiles 4w..4w+3, 2 n-tiles
  _Float16* corrm = (_Float16*)smem;
  const int lane = tid & 63, w = tid >> 6;
  const int ml = lane & 15, qd = lane >> 4;
  float4v vacc[4][2];
  float4v z = {0.f, 0.f, 0.f, 0.f};
#pragma unroll
  for (int im = 0; im < 4; ++im) { vacc[im][0] = z; vacc[im][1] = z; }
#pragma unroll
  for (int ks = 0; ks < 2; ++ks) {
    half8 bfrag[2];
#pragma unroll
    for (int nt = 0; nt < 2; ++nt)
      bfrag[nt] = *(const half8*)(wch + (nt * 16 + ml) * 64 + ks * 32 + qd * 8);
#pragma unroll
    for (int im = 0; im < 4; ++im) {
      half8 afrag = *(const half8*)(corrm + (w * 64 + im * 16 + ml) * 72 + ks * 32 + qd * 8);
#pragma unroll
      for (int nt = 0; nt < 2; ++nt)
        vacc[im][nt] = __builtin_amdgcn_mfma_f32_16x16x32_f16(afrag, bfrag[nt], vacc[im][nt], 0, 0, 0);
    }
  }

  // epilogue: v -> outpre[b, n, h*32+d] fp16 (bias already folded via K=49 column)
#pragma unroll
  for (int im = 0; im < 4; ++im) {
#pragma unroll
    for (int nt = 0; nt < 2; ++nt) {
      int d = nt * 16 + ml;
#pragma unroll
      for (int r = 0; r < 4; ++r) {
        int pos = w * 64 + im * 16 + qd * 4 + r;
        int py = pos >> 4, px = pos & 15;
        int n = t * 1024 + (y0 + py) * 32 + (x0 + px);
        outp[(((size_t)b * 8192 + n) << 8) + h * 32 + d] = (_Float16)vacc[im][nt][r];
      }
    }
  }
}

// ---- proj GEMM: out = op16 @ wproj16^T + b_proj. 128x256 tile = FULL output width.
// Same reg-staged 2-deep pipeline (A fp16: 1 granule/thread).
__global__ __launch_bounds__(512)
void gemm_proj(const _Float16* __restrict__ A, const _Float16* __restrict__ Bw,
               const float* __restrict__ bp, float* __restrict__ out) {
  __shared__ _Float16 Ash[2][4096];
  __shared__ _Float16 Bsh[2][8192];
  const int tid = threadIdx.x;
  const int lane = tid & 63, w = tid >> 6;
  const int wm = w >> 2, wn = w & 3;
  const int ml = lane & 15, qd = lane >> 4;
  const int m0 = blockIdx.x * 128;

  float4v acc[4][4];
  float4v z = {0.f, 0.f, 0.f, 0.f};
#pragma unroll
  for (int i = 0; i < 4; ++i)
#pragma unroll
    for (int j = 0; j < 4; ++j) acc[i][j] = z;

  const _Float16* Ap = A + (size_t)m0 * 256;
  const _Float16* Bp = Bw;
  const int ar = tid >> 2, aj = tid & 3;
  const int ajx = aj ^ ((ar >> 1) & 3);
  const int rB0 = tid >> 2, jB0 = (tid & 3) ^ ((rB0 >> 1) & 3);
  const int rB1 = rB0 + 128, jB1 = (tid & 3) ^ ((rB1 >> 1) & 3);

  uint4 as[2];
  uint4 bs[2][2];

  as[0] = *(const uint4*)(Ap + (size_t)ar * 256 + ajx * 8);
  bs[0][0] = *(const uint4*)(Bp + (size_t)rB0 * 256 + jB0 * 8);
  bs[0][1] = *(const uint4*)(Bp + (size_t)rB1 * 256 + jB1 * 8);
  *(uint4*)(&Ash[0][ar * 32 + aj * 8]) = as[0];
  *(uint4*)(&Bsh[0][tid * 8]) = bs[0][0];
  *(uint4*)(&Bsh[0][(tid + 512) * 8]) = bs[0][1];
  as[1] = *(const uint4*)(Ap + (size_t)ar * 256 + 32 + ajx * 8);
  bs[1][0] = *(const uint4*)(Bp + (size_t)rB0 * 256 + 32 + jB0 * 8);
  bs[1][1] = *(const uint4*)(Bp + (size_t)rB1 * 256 + 32 + jB1 * 8);
  WAITLGKM;
  sbar0();
  __builtin_amdgcn_s_barrier();
  sbar0();

#pragma unroll
  for (int kt = 0; kt < 8; ++kt) {
    const int cur = kt & 1, nbuf = cur ^ 1;
    if (kt < 6) {
      const int kX = (kt + 2) * 32;
      as[kt & 1] = *(const uint4*)(Ap + (size_t)ar * 256 + kX + ajx * 8);
      bs[kt & 1][0] = *(const uint4*)(Bp + (size_t)rB0 * 256 + kX + jB0 * 8);
      bs[kt & 1][1] = *(const uint4*)(Bp + (size_t)rB1 * 256 + kX + jB1 * 8);
      sbar0();
    }
    half8 af[4], bf[4];
#pragma unroll
    for (int im = 0; im < 4; ++im) {
      int rr = wm * 64 + im * 16 + ml;
      af[im] = *(const half8*)(&Ash[cur][rr * 32 + (qd ^ ((rr >> 1) & 3)) * 8]);
      int rc = wn * 64 + im * 16 + ml;
      bf[im] = *(const half8*)(&Bsh[cur][rc * 32 + (qd ^ ((rc >> 1) & 3)) * 8]);
    }
#pragma unroll
    for (int im = 0; im < 4; ++im)
#pragma unroll
      for (int in = 0; in < 4; ++in)
        acc[im][in] = __builtin_amdgcn_mfma_f32_16x16x32_f16(bf[in], af[im], acc[im][in], 0, 0, 0);
    if (kt < 7) {
      *(uint4*)(&Ash[nbuf][ar * 32 + aj * 8]) = as[(kt + 1) & 1];
      *(uint4*)(&Bsh[nbuf][tid * 8]) = bs[(kt + 1) & 1][0];
      *(uint4*)(&Bsh[nbuf][(tid + 512) * 8]) = bs[(kt + 1) & 1][1];
      WAITLGKM;
      sbar0();
      __builtin_amdgcn_s_barrier();
      sbar0();
    }
  }

  // epilogue: lane covers row rowr, 4 consecutive cols -> one 16B store
#pragma unroll
  for (int im = 0; im < 4; ++im) {
    int rowr = m0 + wm * 64 + im * 16 + ml;
#pragma unroll
    for (int in = 0; in < 4; ++in) {
      int col = wn * 64 + in * 16 + qd * 4;
      float4 bb = *(const float4*)(bp + col);
      float4 o;
      o.x = acc[im][in][0] + bb.x;
      o.y = acc[im][in][1] + bb.y;
      o.z = acc[im][in][2] + bb.z;
      o.w = acc[im][in][3] + bb.w;
      *(float4*)(out + (size_t)rowr * 256 + col) = o;
    }
  }
}

extern "C" void kernel_launch(void* const* d_in, const int* in_sizes, int n_in,
                              void* d_out, int out_size, void* d_ws, size_t ws_size,
                              hipStream_t stream) {
  const float* x      = (const float*)d_in[0];
  const float* w_qk   = (const float*)d_in[1];
  const float* w_corr = (const float*)d_in[2];
  const float* b_corr = (const float*)d_in[3];
  const float* w_proj = (const float*)d_in[4];
  const float* b_proj = (const float*)d_in[5];
  float* out = (float*)d_out;

  char* ws = (char*)d_ws;
  _Float16* q16   = (_Float16*)(ws + 33554432);
  _Float16* k16   = (_Float16*)(ws + 67108864);
  _Float16* op16  = (_Float16*)(ws + 100663296);
  _Float16* wqk16 = (_Float16*)(ws + 134217728);
  _Float16* wpj16 = (_Float16*)(ws + 134479872);

  cvt_w<<<192, 256, 0, stream>>>((const float4*)w_qk, (const float4*)w_proj,
                                 (ushort4*)wqk16, (ushort4*)wpj16);
  gemm_qk<<<1024, 512, 0, stream>>>(x, wqk16, q16, k16);
  corr_kernel<<<2048, 256, 0, stream>>>(q16, k16, w_corr, b_corr, op16);
  gemm_proj<<<512, 512, 0, stream>>>(op16, wpj16, b_proj, out);
}